// Round 2
// baseline (1118.238 us; speedup 1.0000x reference)
//
#include <hip/hip_runtime.h>
#include <hip/hip_bf16.h>
#include <math.h>

// Problem constants
#define T_TOK 512
#define H_DIM 2048
#define E_NUM 16
#define K_TOP 4
#define I_DIM 1408
#define IS_DIM 2816

typedef __bf16 bf16;
typedef __attribute__((ext_vector_type(8))) __bf16 bf16x8;
typedef __attribute__((ext_vector_type(4))) float f32x4;

// GEMM tiling
#define BM 128
#define BN 128
#define BK 32

// Load 8 contiguous f32 and convert to bf16x8 (two dwordx4 loads + cvt).
__device__ inline bf16x8 cvt8(const float* __restrict__ p) {
    const f32x4 a = *(const f32x4*)(p);
    const f32x4 b = *(const f32x4*)(p + 4);
    bf16x8 r;
    r[0] = (bf16)a[0]; r[1] = (bf16)a[1]; r[2] = (bf16)a[2]; r[3] = (bf16)a[3];
    r[4] = (bf16)b[0]; r[5] = (bf16)b[1]; r[6] = (bf16)b[2]; r[7] = (bf16)b[3];
    return r;
}

// ---------------------------------------------------------------------------
// Router: logits = x @ gate_w.T in full f32 (matches np reference selection);
// softmax -> top4 -> renormalize. One wave per token. The softmax denominator
// cancels under top-k renormalization: rank/renormalize exp(logit - max).
// ---------------------------------------------------------------------------
__global__ __launch_bounds__(64) void router_kernel(
    const float* __restrict__ x, const float* __restrict__ gw,
    int* __restrict__ counts, int* __restrict__ tok_id, float* __restrict__ tok_w)
{
    int t = blockIdx.x;
    int lane = threadIdx.x;
    float acc[E_NUM];
#pragma unroll
    for (int e = 0; e < E_NUM; e++) acc[e] = 0.f;
    for (int h = lane; h < H_DIM; h += 64) {
        float xv = x[t * H_DIM + h];
#pragma unroll
        for (int e = 0; e < E_NUM; e++) acc[e] += xv * gw[e * H_DIM + h];
    }
#pragma unroll
    for (int e = 0; e < E_NUM; e++) {
#pragma unroll
        for (int off = 32; off; off >>= 1) acc[e] += __shfl_xor(acc[e], off);
    }
    if (lane == 0) {
        float m = acc[0];
#pragma unroll
        for (int e = 1; e < E_NUM; e++) m = fmaxf(m, acc[e]);
        float p[E_NUM];
#pragma unroll
        for (int e = 0; e < E_NUM; e++) p[e] = __expf(acc[e] - m);
        int sel[K_TOP];
        float pw[K_TOP];
        float wsum = 0.f;
        bool used[E_NUM];
#pragma unroll
        for (int e = 0; e < E_NUM; e++) used[e] = false;
        for (int k = 0; k < K_TOP; k++) {
            int best = 0;
            float bv = -1.f;
            for (int e = 0; e < E_NUM; e++) {
                if (!used[e] && p[e] > bv) { bv = p[e]; best = e; }
            }
            used[best] = true;
            sel[k] = best;
            pw[k] = bv;
            wsum += bv;
        }
        float inv = 1.f / wsum;
        for (int k = 0; k < K_TOP; k++) {
            int e = sel[k];
            int pos = atomicAdd(&counts[e], 1);
            tok_id[e * T_TOK + pos] = t;
            tok_w[e * T_TOK + pos] = pw[k] * inv;  // SCALE == 1.0
        }
    }
}

// ---------------------------------------------------------------------------
// gate_up GEMM (paired): C_g = A @ Wg^T, C_u = A @ Wu^T, out = silu(g)*u*wgt.
// f32 inputs converted to bf16 during LDS staging; MFMA bf16, f32 accumulate.
// A rows gathered via token list when GATHER. NT layout: both operands
// K-contiguous (K = H_DIM).
// ---------------------------------------------------------------------------
template <bool GATHER>
__global__ __launch_bounds__(256) void gateup_kernel(
    const float* __restrict__ X,       // [T,H] f32
    const float* __restrict__ W,       // expert-strided gate_up weights, f32
    long w_expert_stride,              // elements per expert (2I*H) or 0
    int pair_off_rows,                 // I or IS (u-row offset)
    bf16* __restrict__ Hout,           // output intermediate (bf16 ws)
    long h_expert_stride,              // T*I or 0
    int ldh,                           // I or IS
    const int* __restrict__ counts,
    const int* __restrict__ tok_id,
    const float* __restrict__ tok_w)
{
    int e = blockIdx.z;
    int n0 = blockIdx.x * BN;
    int m0 = blockIdx.y * BM;
    int count;
    if constexpr (GATHER) count = counts[e]; else count = T_TOK;
    if (m0 >= count) return;

    const float* Wg = W + (long)e * w_expert_stride;
    const float* Wu = Wg + (long)pair_off_rows * H_DIM;
    bf16* Ho = Hout + (long)e * h_expert_stride;
    const int* tid_p = nullptr;
    const float* tw_p = nullptr;
    if constexpr (GATHER) {
        tid_p = tok_id + e * T_TOK;
        tw_p = tok_w + e * T_TOK;
    }

    __shared__ bf16 sA[BM * BK];
    __shared__ bf16 sG[BN * BK];
    __shared__ bf16 sU[BN * BK];

    int tidx = threadIdx.x;
    int lane = tidx & 63;
    int wv = tidx >> 6;
    int wm = wv >> 1, wn = wv & 1;

    f32x4 accG[4][4], accU[4][4];
#pragma unroll
    for (int i = 0; i < 4; i++)
#pragma unroll
        for (int j = 0; j < 4; j++) {
            accG[i][j] = (f32x4){0.f, 0.f, 0.f, 0.f};
            accU[i][j] = (f32x4){0.f, 0.f, 0.f, 0.f};
        }

    // Staging: tile = 4096 bf16 = 512 chunks of 8 elems; thread stages chunks
    // tidx and tidx+256. chunk c -> row c>>2, cols (c&3)*8..+8.
    long arow_off[2], wrow_off[2];
#pragma unroll
    for (int c2 = 0; c2 < 2; c2++) {
        int c = tidx + c2 * 256;
        int row = c >> 2;
        int tok;
        if constexpr (GATHER) {
            int idx = m0 + row;
            tok = (idx < count) ? tid_p[idx] : tid_p[0];
        } else {
            tok = m0 + row;
        }
        arow_off[c2] = (long)tok * H_DIM + (c & 3) * 8;
        wrow_off[c2] = (long)(n0 + row) * H_DIM + (c & 3) * 8;
    }

    const int ktiles = H_DIM / BK;
    for (int kt = 0; kt < ktiles; kt++) {
        int k0 = kt * BK;
#pragma unroll
        for (int c2 = 0; c2 < 2; c2++) {
            int c = tidx + c2 * 256;
            int ldsoff = c * 8;
            *(bf16x8*)&sA[ldsoff] = cvt8(&X[arow_off[c2] + k0]);
            *(bf16x8*)&sG[ldsoff] = cvt8(&Wg[wrow_off[c2] + k0]);
            *(bf16x8*)&sU[ldsoff] = cvt8(&Wu[wrow_off[c2] + k0]);
        }
        __syncthreads();
        int quad = lane >> 4, l16 = lane & 15;
        bf16x8 aF[4], gF[4], uF[4];
#pragma unroll
        for (int mt = 0; mt < 4; mt++)
            aF[mt] = *(const bf16x8*)&sA[(wm * 64 + mt * 16 + l16) * BK + quad * 8];
#pragma unroll
        for (int nt = 0; nt < 4; nt++) {
            gF[nt] = *(const bf16x8*)&sG[(wn * 64 + nt * 16 + l16) * BK + quad * 8];
            uF[nt] = *(const bf16x8*)&sU[(wn * 64 + nt * 16 + l16) * BK + quad * 8];
        }
#pragma unroll
        for (int mt = 0; mt < 4; mt++)
#pragma unroll
            for (int nt = 0; nt < 4; nt++) {
                accG[mt][nt] = __builtin_amdgcn_mfma_f32_16x16x32_bf16(aF[mt], gF[nt], accG[mt][nt], 0, 0, 0);
                accU[mt][nt] = __builtin_amdgcn_mfma_f32_16x16x32_bf16(aF[mt], uF[nt], accU[mt][nt], 0, 0, 0);
            }
        __syncthreads();
    }

    // Epilogue: h = silu(g)*u*wgt, stored bf16. C/D layout: col=lane&15, row=quad*4+r.
    int quad = lane >> 4, l16 = lane & 15;
#pragma unroll
    for (int mt = 0; mt < 4; mt++) {
#pragma unroll
        for (int r = 0; r < 4; r++) {
            int row = m0 + wm * 64 + mt * 16 + quad * 4 + r;
            if (row < count) {
                float wgt = 1.f;
                if constexpr (GATHER) wgt = tw_p[row];
#pragma unroll
                for (int nt = 0; nt < 4; nt++) {
                    int col = n0 + wn * 64 + nt * 16 + l16;
                    float g = accG[mt][nt][r];
                    float u = accU[mt][nt][r];
                    float sig = 1.f / (1.f + __expf(-g));
                    float h = g * sig * u * wgt;
                    Ho[(long)row * ldh + col] = (bf16)h;
                }
            }
        }
    }
}

// ---------------------------------------------------------------------------
// down GEMM: C = A @ Wd^T. A = bf16 intermediate (direct 16B LDS copy),
// W = f32 weights (cvt during staging). GATHER: scatter-atomicAdd to
// out[token] (f32). !GATHER: plain f32 store (runs first, initializes out).
// ---------------------------------------------------------------------------
template <bool GATHER>
__global__ __launch_bounds__(256) void down_kernel(
    const bf16* __restrict__ Hin,      // intermediate base (bf16)
    long h_expert_stride, int ldh, int Kdim,
    const float* __restrict__ W,       // down weights f32, rows along Kdim
    long w_expert_stride,
    float* __restrict__ out,           // [T,H] f32 output
    const int* __restrict__ counts,
    const int* __restrict__ tok_id)
{
    int e = blockIdx.z;
    int n0 = blockIdx.x * BN;   // over H_DIM
    int m0 = blockIdx.y * BM;
    int count;
    if constexpr (GATHER) count = counts[e]; else count = T_TOK;
    if (m0 >= count) return;

    const bf16* A = Hin + (long)e * h_expert_stride;
    const float* B = W + (long)e * w_expert_stride;
    const int* tid_p = nullptr;
    if constexpr (GATHER) tid_p = tok_id + e * T_TOK;

    __shared__ bf16 sA[BM * BK];
    __shared__ bf16 sB[BN * BK];

    int tidx = threadIdx.x;
    int lane = tidx & 63;
    int wv = tidx >> 6;
    int wm = wv >> 1, wn = wv & 1;

    f32x4 acc[4][4];
#pragma unroll
    for (int i = 0; i < 4; i++)
#pragma unroll
        for (int j = 0; j < 4; j++) acc[i][j] = (f32x4){0.f, 0.f, 0.f, 0.f};

    long arow_off[2], brow_off[2];
#pragma unroll
    for (int c2 = 0; c2 < 2; c2++) {
        int c = tidx + c2 * 256;
        int row = c >> 2;
        arow_off[c2] = (long)(m0 + row) * ldh + (c & 3) * 8;
        brow_off[c2] = (long)(n0 + row) * Kdim + (c & 3) * 8;
    }

    const int ktiles = Kdim / BK;
    for (int kt = 0; kt < ktiles; kt++) {
        int k0 = kt * BK;
#pragma unroll
        for (int c2 = 0; c2 < 2; c2++) {
            int c = tidx + c2 * 256;
            int ldsoff = c * 8;
            *(bf16x8*)&sA[ldsoff] = *(const bf16x8*)&A[arow_off[c2] + k0];
            *(bf16x8*)&sB[ldsoff] = cvt8(&B[brow_off[c2] + k0]);
        }
        __syncthreads();
        int quad = lane >> 4, l16 = lane & 15;
        bf16x8 aF[4], bF[4];
#pragma unroll
        for (int mt = 0; mt < 4; mt++)
            aF[mt] = *(const bf16x8*)&sA[(wm * 64 + mt * 16 + l16) * BK + quad * 8];
#pragma unroll
        for (int nt = 0; nt < 4; nt++)
            bF[nt] = *(const bf16x8*)&sB[(wn * 64 + nt * 16 + l16) * BK + quad * 8];
#pragma unroll
        for (int mt = 0; mt < 4; mt++)
#pragma unroll
            for (int nt = 0; nt < 4; nt++)
                acc[mt][nt] = __builtin_amdgcn_mfma_f32_16x16x32_bf16(aF[mt], bF[nt], acc[mt][nt], 0, 0, 0);
        __syncthreads();
    }

    int quad = lane >> 4, l16 = lane & 15;
#pragma unroll
    for (int mt = 0; mt < 4; mt++) {
#pragma unroll
        for (int r = 0; r < 4; r++) {
            int row = m0 + wm * 64 + mt * 16 + quad * 4 + r;
            if (row < count) {
#pragma unroll
                for (int nt = 0; nt < 4; nt++) {
                    int col = n0 + wn * 64 + nt * 16 + l16;
                    float v = acc[mt][nt][r];
                    if constexpr (GATHER) {
                        int tok = tid_p[row];
                        atomicAdd(&out[(long)tok * H_DIM + col], v);
                    } else {
                        out[(long)row * H_DIM + col] = v;
                    }
                }
            }
        }
    }
}

// ---------------------------------------------------------------------------
// Workspace layout (bytes):
//   0        counts        (E ints, padded to 256)
//   256      tok_id        (E*T ints   = 32768)
//   33024    tok_w         (E*T floats = 32768)
//   65792    hshared       (T*IS bf16  = 2883584)
//   2949376  hrouted       (E*T*I bf16 = 23068672)
//   total ~26.0 MB
// ---------------------------------------------------------------------------
extern "C" void kernel_launch(void* const* d_in, const int* in_sizes, int n_in,
                              void* d_out, int out_size, void* d_ws, size_t ws_size,
                              hipStream_t stream)
{
    const float* x              = (const float*)d_in[0];
    const float* gate_w         = (const float*)d_in[1];
    const float* w_gate_up      = (const float*)d_in[2];
    const float* w_down         = (const float*)d_in[3];
    const float* shared_gate_up = (const float*)d_in[4];
    const float* shared_down    = (const float*)d_in[5];
    float* out = (float*)d_out;

    char* ws = (char*)d_ws;
    int*   counts  = (int*)(ws + 0);
    int*   tok_id  = (int*)(ws + 256);
    float* tok_w   = (float*)(ws + 33024);
    bf16*  hshared = (bf16*)(ws + 65792);
    bf16*  hrouted = (bf16*)(ws + 2949376);

    hipMemsetAsync(counts, 0, E_NUM * sizeof(int), stream);

    router_kernel<<<T_TOK, 64, 0, stream>>>(x, gate_w, counts, tok_id, tok_w);

    // shared gate_up: N=IS, K=H; identity rows
    gateup_kernel<false><<<dim3(IS_DIM / BN, T_TOK / BM, 1), 256, 0, stream>>>(
        x, shared_gate_up, 0L, IS_DIM, hshared, 0L, IS_DIM, nullptr, nullptr, nullptr);

    // routed gate_up: N=I, K=H; gathered rows, combine weight fused
    gateup_kernel<true><<<dim3(I_DIM / BN, T_TOK / BM, E_NUM), 256, 0, stream>>>(
        x, w_gate_up, (long)2 * I_DIM * H_DIM, I_DIM, hrouted, (long)T_TOK * I_DIM, I_DIM,
        counts, tok_id, tok_w);

    // shared down: K=IS, N=H; plain store initializes out fully
    down_kernel<false><<<dim3(H_DIM / BN, T_TOK / BM, 1), 256, 0, stream>>>(
        hshared, 0L, IS_DIM, IS_DIM, shared_down, 0L, out, nullptr, nullptr);

    // routed down: K=I, N=H; atomicAdd scatter by token
    down_kernel<true><<<dim3(H_DIM / BN, T_TOK / BM, E_NUM), 256, 0, stream>>>(
        hrouted, (long)T_TOK * I_DIM, I_DIM, I_DIM, w_down, (long)H_DIM * I_DIM, out,
        counts, tok_id);
}